// Round 10
// baseline (1135.251 us; speedup 1.0000x reference)
//
#include <hip/hip_runtime.h>
#include <hip/hip_bf16.h>

#define DEVI __device__ __forceinline__

typedef __attribute__((ext_vector_type(8))) __bf16 bf16x8;
typedef __attribute__((ext_vector_type(4))) float f32x4;
typedef __attribute__((ext_vector_type(8))) unsigned short ushort8;

DEVI unsigned short f2bf(float f) {
    union { float f; unsigned u; } v; v.f = f;
    unsigned r = v.u + 0x7fffu + ((v.u >> 16) & 1u);
    return (unsigned short)(r >> 16);
}

DEVI void load_lds_16(const void* g, void* l) {
    __builtin_amdgcn_global_load_lds(
        (const __attribute__((address_space(1))) void*)g,
        (__attribute__((address_space(3))) void*)l, 16, 0, 0);
}

// ---------------- weight transpose+convert: in [K][N] f32 -> out [N][K] bf16 ----------------
__global__ __launch_bounds__(256) void k_transpose_w(const float* __restrict__ in,
                                                     unsigned short* __restrict__ out,
                                                     int K, int N) {
    __shared__ float tile[64][65];
    const int tk = blockIdx.x * 64, tn = blockIdx.y * 64;
    const int t = threadIdx.x;
    const int c4 = (t & 15) * 4, r0 = t >> 4;
#pragma unroll
    for (int p = 0; p < 4; ++p) {
        int r = r0 + p * 16;
        float4 v = *reinterpret_cast<const float4*>(&in[(size_t)(tk + r) * N + tn + c4]);
        tile[r][c4 + 0] = v.x; tile[r][c4 + 1] = v.y;
        tile[r][c4 + 2] = v.z; tile[r][c4 + 3] = v.w;
    }
    __syncthreads();
#pragma unroll
    for (int p = 0; p < 4; ++p) {
        int n = r0 + p * 16;
        ushort4 o;
        o.x = f2bf(tile[c4 + 0][n]); o.y = f2bf(tile[c4 + 1][n]);
        o.z = f2bf(tile[c4 + 2][n]); o.w = f2bf(tile[c4 + 3][n]);
        *reinterpret_cast<ushort4*>(&out[(size_t)(tn + n) * K + tk + c4]) = o;
    }
}

// ---------------- V transpose: qkv bf16 V-part [s][d] -> vt [bh][d][s] bf16 ----------------
__global__ __launch_bounds__(256) void k_transpose_v(const unsigned short* __restrict__ qkv,
                                                     unsigned short* __restrict__ vt) {
    __shared__ unsigned short tile[64][72];
    const int ts = blockIdx.x * 64;   // s tile
    const int td = blockIdx.y * 64;   // d tile
    const int bh = blockIdx.z;
    const int b = bh >> 4, h = bh & 15;
    const unsigned short* src = qkv + (size_t)b * 2048 * 6144 + 4096 + h * 128;
    const int t = threadIdx.x;
    const int c8 = (t & 7) * 8, r0 = t >> 3; // r0: 0..31
#pragma unroll
    for (int p = 0; p < 2; ++p) {
        int r = r0 + p * 32;
        const unsigned short* sp = &src[(size_t)(ts + r) * 6144 + td + c8];
        ushort4 a0 = *reinterpret_cast<const ushort4*>(sp);
        ushort4 a1 = *reinterpret_cast<const ushort4*>(sp + 4);
        tile[r][c8 + 0] = a0.x; tile[r][c8 + 1] = a0.y; tile[r][c8 + 2] = a0.z; tile[r][c8 + 3] = a0.w;
        tile[r][c8 + 4] = a1.x; tile[r][c8 + 5] = a1.y; tile[r][c8 + 6] = a1.z; tile[r][c8 + 7] = a1.w;
    }
    __syncthreads();
    unsigned short* dst = vt + ((size_t)bh * 128 + td) * 2048 + ts;
#pragma unroll
    for (int p = 0; p < 2; ++p) {
        int d = r0 + p * 32;
        ushort4 o0, o1;
        o0.x = tile[c8 + 0][d]; o0.y = tile[c8 + 1][d]; o0.z = tile[c8 + 2][d]; o0.w = tile[c8 + 3][d];
        o1.x = tile[c8 + 4][d]; o1.y = tile[c8 + 5][d]; o1.z = tile[c8 + 6][d]; o1.w = tile[c8 + 7][d];
        *reinterpret_cast<ushort4*>(&dst[(size_t)d * 2048 + c8]) = o0;
        *reinterpret_cast<ushort4*>(&dst[(size_t)d * 2048 + c8 + 4]) = o1;
    }
}

// ---------------- layernorm: fp32 [rows][2048] -> bf16, one block per row ----------------
__global__ __launch_bounds__(256) void k_layernorm(const float* __restrict__ x,
                                                   const float* __restrict__ g,
                                                   const float* __restrict__ bb,
                                                   unsigned short* __restrict__ out) {
    const int row = blockIdx.x;
    const int t = threadIdx.x;
    const float* xr = x + (size_t)row * 2048 + t * 8;
    float4 v0 = *reinterpret_cast<const float4*>(xr);
    float4 v1 = *reinterpret_cast<const float4*>(xr + 4);
    float s = (v0.x + v0.y) + (v0.z + v0.w) + (v1.x + v1.y) + (v1.z + v1.w);
    float ss = (v0.x * v0.x + v0.y * v0.y) + (v0.z * v0.z + v0.w * v0.w)
             + (v1.x * v1.x + v1.y * v1.y) + (v1.z * v1.z + v1.w * v1.w);
#pragma unroll
    for (int m = 1; m < 64; m <<= 1) { s += __shfl_xor(s, m); ss += __shfl_xor(ss, m); }
    __shared__ float red[8];
    if ((t & 63) == 0) { red[t >> 6] = s; red[4 + (t >> 6)] = ss; }
    __syncthreads();
    s = (red[0] + red[1]) + (red[2] + red[3]);
    ss = (red[4] + red[5]) + (red[6] + red[7]);
    const float mu = s * (1.f / 2048.f);
    const float rstd = rsqrtf(ss * (1.f / 2048.f) - mu * mu + 1e-5f);
    const float4 g0 = *reinterpret_cast<const float4*>(g + t * 8);
    const float4 g1 = *reinterpret_cast<const float4*>(g + t * 8 + 4);
    const float4 b0 = *reinterpret_cast<const float4*>(bb + t * 8);
    const float4 b1 = *reinterpret_cast<const float4*>(bb + t * 8 + 4);
    ushort8 o;
    o[0] = f2bf((v0.x - mu) * rstd * g0.x + b0.x);
    o[1] = f2bf((v0.y - mu) * rstd * g0.y + b0.y);
    o[2] = f2bf((v0.z - mu) * rstd * g0.z + b0.z);
    o[3] = f2bf((v0.w - mu) * rstd * g0.w + b0.w);
    o[4] = f2bf((v1.x - mu) * rstd * g1.x + b1.x);
    o[5] = f2bf((v1.y - mu) * rstd * g1.y + b1.y);
    o[6] = f2bf((v1.z - mu) * rstd * g1.z + b1.z);
    o[7] = f2bf((v1.w - mu) * rstd * g1.w + b1.w);
    *reinterpret_cast<ushort8*>(out + (size_t)row * 2048 + t * 8) = o;
}

// ======================= GEMM 256x256, 8-wave, 8-PHASE + READ-AHEAD =======================
// A[M][K] bf16 * Bt[N][K] bf16 + bias. K-half LDS slots: per operand 4 slots of 16KB
// (slot = buf*2 + khalf). Pairline layout: pairline p (128B) holds rows {2p,2p+1} of a
// 32-k half; physical granule g' = ((rowparity<<2)|kgranule) ^ (p&7). Staging is linear
// (global_load_lds dest = base + lane*16) with pre-swizzled per-lane global source.
// R10 change: REGISTER READ-AHEAD. Phase k issues the ds_reads for quadrant k+1's
// fragments, then MFMAs quadrant k from registers loaded last phase. The 4-8 reads
// drain on the LDS pipe WHILE the matrix pipe runs (previously the two windows were
// barrier-disjoint -> serial 620+576 cyc/phase). Slot publication: every slot is
// staged 5 phases before its first read; vmcnt(6) at each phase tail retires loads
// >=3 phases old (FIFO-verified incl. prologue bunching), so the tail barrier
// publishes each slot at least one phase before its read. WAR safe: a slot's last
// reads are lgkm-consumed by the MFMA before that wave passes the barrier preceding
// the slot's re-stage.
template <int EPI>
__global__ __launch_bounds__(512, 1) void k_gemm256(const unsigned short* __restrict__ A,
                                                    const unsigned short* __restrict__ Bt,
                                                    const float* __restrict__ bias,
                                                    const float* __restrict__ res,
                                                    void* __restrict__ outv,
                                                    int M, int N, int K,
                                                    int scale_cols, float scale, int gx) {
    __shared__ alignas(16) unsigned short LDS[65536];   // A: bytes [0,64K), B: [64K,128K)

    // bijective XCD swizzle (nwg % 8 == 0 for all our grids)
    const int nwg = gridDim.x;
    const int bid = blockIdx.x;
    const int wg = (bid & 7) * (nwg >> 3) + (bid >> 3);
    const int bn = (wg % gx) * 256;
    const int bm = (wg / gx) * 256;

    const int t = threadIdx.x, lane = t & 63, wid = t >> 6;
    const int wr = wid >> 2, wn = wid & 3;          // wave: row-half (0,1) x col-quarter (0..3)
    const int l15 = lane & 15, l4 = lane >> 4;      // frag: row=l15, k-granule=l4

    // ds_read thread base within a 16KB slot: q=l15>>1, rp=l15&1, g'=((rp<<2)|l4)^q
    const int q_ = l15 >> 1, rp_ = l15 & 1;
    const int Toff = q_ * 128 + (((((rp_ << 2) | l4)) ^ q_) << 4);
    const char* pTA = (const char*)LDS + wr * 8192 + Toff;
    const char* pTB = (const char*)LDS + 65536 + wn * 4096 + Toff;

    // staging source mapping: lane covers pairline (wid*2+i)*8 + (lane>>3), phys granule lane&7
    const int glog = (lane & 7) ^ (lane >> 3);
    const int s_rp = glog >> 2, s_j = glog & 3;
    const int s_row = wid * 32 + 2 * (lane >> 3) + s_rp;     // +16 for i=1
    const unsigned short* pAs0 = A  + (size_t)(bm + s_row) * K + s_j * 8;
    const unsigned short* pAs1 = pAs0 + (size_t)16 * K;
    const unsigned short* pBs0 = Bt + (size_t)(bn + s_row) * K + s_j * 8;
    const unsigned short* pBs1 = pBs0 + (size_t)16 * K;
    char* dA = (char*)LDS + wid * 2048;            // + SLOT*16384 (+1024 for i=1)
    char* dB = (char*)LDS + 65536 + wid * 2048;

    const int NT = K >> 6;
    const int NI = NT >> 1;     // >= 2 for all our shapes

    f32x4 acc[8][4] = {};
    bf16x8 A0f[4], A1f[4], B0f[4], B1f[4];

#define STGA(SLOT, KOE) do { \
    load_lds_16(pAs0 + (KOE), dA + (SLOT) * 16384); \
    load_lds_16(pAs1 + (KOE), dA + (SLOT) * 16384 + 1024); } while (0)
#define STGB(SLOT, KOE) do { \
    load_lds_16(pBs0 + (KOE), dB + (SLOT) * 16384); \
    load_lds_16(pBs1 + (KOE), dB + (SLOT) * 16384 + 1024); } while (0)
#define RDA4(DST, SLOT, F0) do { _Pragma("unroll") \
    for (int f_ = 0; f_ < 4; ++f_) \
        DST[f_] = *reinterpret_cast<const bf16x8*>(pTA + (SLOT) * 16384 + ((F0) + f_) * 1024); } while (0)
#define RDB4(DST, SLOT) do { _Pragma("unroll") \
    for (int n_ = 0; n_ < 4; ++n_) \
        DST[n_] = *reinterpret_cast<const bf16x8*>(pTB + (SLOT) * 16384 + n_ * 1024); } while (0)
#define MM16(F0, AV, BV) do { _Pragma("unroll") \
    for (int f_ = 0; f_ < 4; ++f_) \
        _Pragma("unroll") \
        for (int n_ = 0; n_ < 4; ++n_) \
            acc[(F0) + f_][n_] = __builtin_amdgcn_mfma_f32_16x16x32_bf16( \
                AV[f_], BV[n_], acc[(F0) + f_][n_], 0, 0, 0); } while (0)
// Phase: stage; READ-AHEAD for next quadrant; barrier; MFMA current quadrant
// (regs loaded LAST phase -> no lgkm gate; reads drain under MFMA); tail.
#define PH(STG, RDS, F0, AV, BV, TAIL) do { \
    STG; RDS; \
    asm volatile("s_barrier" ::: "memory"); \
    __builtin_amdgcn_s_setprio(1); \
    MM16(F0, AV, BV); \
    __builtin_amdgcn_s_setprio(0); \
    TAIL; } while (0)
#define VM6 asm volatile("s_waitcnt vmcnt(6)\n\ts_barrier" ::: "memory")
#define VM0 asm volatile("s_waitcnt vmcnt(0)\n\ts_barrier" ::: "memory")
#define BAR asm volatile("s_barrier" ::: "memory")
#define NOST ((void)0)

    // prologue: slot0=KT0.kh0, slot1=KT0.kh1, slot2=KT1.kh0 (12 loads, FIFO order);
    // vmcnt(8) retires slot0 -> barrier publishes it -> pre-read quadrant-1 frags.
    STGA(0, 0);  STGB(0, 0);
    STGA(1, 32); STGB(1, 32);
    STGA(2, 64); STGB(2, 64);
    asm volatile("s_waitcnt vmcnt(8)\n\ts_barrier" ::: "memory");
    RDB4(B0f, 0); RDA4(A0f, 0, 0);

    int kof = 0;
    for (int i = 0; i < NI - 1; ++i, kof += 128) {
        PH(STGA(3, kof +  96), RDA4(A1f, 0, 4),               0, A0f, B0f, VM6);
        PH(STGB(3, kof +  96), RDB4(B1f, 1); RDA4(A0f, 1, 0), 4, A1f, B0f, VM6);
        PH(STGA(0, kof + 128), RDA4(A1f, 1, 4),               0, A0f, B1f, VM6);
        PH(STGB(0, kof + 128), RDB4(B0f, 2); RDA4(A0f, 2, 0), 4, A1f, B1f, VM6);
        PH(STGA(1, kof + 160), RDA4(A1f, 2, 4),               0, A0f, B0f, VM6);
        PH(STGB(1, kof + 160), RDB4(B1f, 3); RDA4(A0f, 3, 0), 4, A1f, B0f, VM6);
        PH(STGA(2, kof + 192), RDA4(A1f, 3, 4),               0, A0f, B1f, VM6);
        PH(STGB(2, kof + 192), RDB4(B0f, 0); RDA4(A0f, 0, 0), 4, A1f, B1f, VM6);
    }
    // final iteration: stage only slot3 (KT(NT-1).kh1); drain at fph2; stage-free tail
    PH(STGA(3, kof + 96), RDA4(A1f, 0, 4),               0, A0f, B0f, VM6);
    PH(STGB(3, kof + 96), RDB4(B1f, 1); RDA4(A0f, 1, 0), 4, A1f, B0f, VM0);
    PH(NOST,              RDA4(A1f, 1, 4),               0, A0f, B1f, BAR);
    PH(NOST,              RDB4(B0f, 2); RDA4(A0f, 2, 0), 4, A1f, B1f, BAR);
    PH(NOST,              RDA4(A1f, 2, 4),               0, A0f, B0f, BAR);
    PH(NOST,              RDB4(B1f, 3); RDA4(A0f, 3, 0), 4, A1f, B0f, BAR);
    PH(NOST,              RDA4(A1f, 3, 4),               0, A0f, B1f, BAR);
    __builtin_amdgcn_s_setprio(1);
    MM16(4, A1f, B1f);
    __builtin_amdgcn_s_setprio(0);

#undef STGA
#undef STGB
#undef RDA4
#undef RDB4
#undef MM16
#undef PH
#undef VM6
#undef VM0
#undef BAR
#undef NOST

    // epilogue
    const int row0 = bm + wr * 128 + l4 * 4;
    const int col0 = bn + wn * 64 + l15;
#pragma unroll
    for (int n = 0; n < 4; ++n) {
        const int col = col0 + n * 16;
        const float bv = bias[col];
        const float qs = (EPI == 0 && col < scale_cols) ? scale : 1.f;
#pragma unroll
        for (int f = 0; f < 8; ++f) {
            const int row = row0 + f * 16;
#pragma unroll
            for (int j = 0; j < 4; ++j) {
                float v = acc[f][n][j] + bv;
                const size_t idx = (size_t)(row + j) * N + col;
                if (EPI == 0) {
                    ((unsigned short*)outv)[idx] = f2bf(v * qs);
                } else if (EPI == 1) {
                    ((float*)outv)[idx] = v + res[idx];
                } else {
                    float u = v + 0.044715f * v * v * v;
                    u = fminf(fmaxf(u, -40.f), 40.f);
                    float e = __expf(1.5957691216057308f * u); // 2*sqrt(2/pi)
                    float th = (e - 1.f) / (e + 1.f);
                    ((unsigned short*)outv)[idx] = f2bf(0.5f * v * (1.f + th));
                }
            }
        }
    }
}

// ---------------- flash attention v2: LDS-staged K/V, dbuf, pair-balanced, causal ----------------
// grid = 1024: xcd = blk&7, idx = blk>>3, bh = xcd*8 + idx/16, pair = idx%16.
// Block handles q-tiles {31-pair, pair} (64 rows each) => uniform 33 k-tile iters.
__global__ __launch_bounds__(256) void k_attn(const unsigned short* __restrict__ qkv,
                                              const unsigned short* __restrict__ vt,
                                              unsigned short* __restrict__ out) {
    __shared__ alignas(16) unsigned short Ks[2][64 * 128];   // [s][d], granule-swizzled
    __shared__ alignas(16) unsigned short Vs[2][128 * 64];   // [d][s], granule-swizzled
    __shared__ alignas(16) unsigned short P_lds[4][16][72];

    const int p = blockIdx.x;
    const int bh = (p & 7) * 8 + ((p >> 3) >> 4);
    const int pair = (p >> 3) & 15;
    const int b = bh >> 4, h = bh & 15;
    const int t = threadIdx.x, lane = t & 63, wid = t >> 6;
    const int l15 = lane & 15, l4 = lane >> 4;

    // staging geometry (per wave: 4 K-chunks + 4 V-chunks of 1KB)
    const int kq = wid * 4;                 // first chunk index of this wave
    const int k_r0 = kq * 4 + (lane >> 4);  // K row for chunk kq (+i*4)
    const int k_g0 = lane & 15;             // physical granule (16B) within K row
    const int v_d0 = kq * 8 + (lane >> 3);  // V row (d) for chunk kq (+i*8)
    const int v_g0 = lane & 7;              // physical granule within V row

#pragma unroll
    for (int qi = 0; qi < 2; ++qi) {
        const int qt = qi ? pair : (31 - pair);
        const int qrow0 = qt * 64 + wid * 16;
        const int nt = qt + 1;

        // Q fragments (A-operand): row l15, k = l4*8 + s*32
        const unsigned short* qp = qkv + (size_t)(b * 2048 + qrow0 + l15) * 6144 + h * 128 + l4 * 8;
        bf16x8 aQ[4];
#pragma unroll
        for (int s = 0; s < 4; ++s) aQ[s] = *reinterpret_cast<const bf16x8*>(qp + s * 32);

        f32x4 oacc[8] = {};
        float m_run[4], l_run[4];
#pragma unroll
        for (int j = 0; j < 4; ++j) { m_run[j] = -1e30f; l_run[j] = 0.f; }

        // prologue: stage tile 0 into buffer 0
        {
#pragma unroll
            for (int i = 0; i < 4; ++i) {
                const int r = k_r0 + i * 4;
                const unsigned short* src = qkv + (size_t)(b * 2048 + r) * 6144 + 2048
                                            + h * 128 + (size_t)(k_g0 ^ (r & 7)) * 8;
                load_lds_16(src, &Ks[0][(kq + i) * 512]);
            }
#pragma unroll
            for (int i = 0; i < 4; ++i) {
                const int d = v_d0 + i * 8;
                const unsigned short* src = vt + ((size_t)bh * 128 + d) * 2048
                                            + (size_t)(v_g0 ^ (d & 7)) * 8;
                load_lds_16(src, &Vs[0][(kq + i) * 512]);
            }
        }

        for (int ti = 0; ti < nt; ++ti) {
            const int cur = ti & 1;
            const int k0 = ti * 64;
            if (ti + 1 < nt) {
                const int kn = k0 + 64;
#pragma unroll
                for (int i = 0; i < 4; ++i) {
                    const int r = k_r0 + i * 4;
                    const unsigned short* src = qkv + (size_t)(b * 2048 + kn + r) * 6144 + 2048
                                                + h * 128 + (size_t)(k_g0 ^ (r & 7)) * 8;
                    load_lds_16(src, &Ks[cur ^ 1][(kq + i) * 512]);
                }
#pragma unroll
                for (int i = 0; i < 4; ++i) {
                    const int d = v_d0 + i * 8;
                    const unsigned short* src = vt + ((size_t)bh * 128 + d) * 2048 + kn
                                                + (size_t)(v_g0 ^ (d & 7)) * 8;
                    load_lds_16(src, &Vs[cur ^ 1][(kq + i) * 512]);
                }
                asm volatile("s_waitcnt vmcnt(8)\n\ts_barrier" ::: "memory");
            } else {
                asm volatile("s_waitcnt vmcnt(0)\n\ts_barrier" ::: "memory");
            }

            // ---- QK^T from LDS ----
            f32x4 sc[4] = {};
#pragma unroll
            for (int s = 0; s < 4; ++s)
#pragma unroll
                for (int ct = 0; ct < 4; ++ct) {
                    bf16x8 bK = *reinterpret_cast<const bf16x8*>(
                        &Ks[cur][(ct * 16 + l15) * 128 + (((s * 4 + l4) ^ (l15 & 7)) << 3)]);
                    sc[ct] = __builtin_amdgcn_mfma_f32_16x16x32_bf16(aQ[s], bK, sc[ct], 0, 0, 0);
                }

            if (k0 + 63 > qrow0) { // causal mask for diagonal-crossing tiles
#pragma unroll
                for (int ct = 0; ct < 4; ++ct) {
                    int colc = k0 + ct * 16 + l15;
#pragma unroll
                    for (int j = 0; j < 4; ++j)
                        if (colc > qrow0 + l4 * 4 + j) sc[ct][j] = -1e30f;
                }
            }
            // ---- online softmax ----
            float alpha[4], tsum[4];
#pragma unroll
            for (int j = 0; j < 4; ++j) {
                float mx = fmaxf(fmaxf(sc[0][j], sc[1][j]), fmaxf(sc[2][j], sc[3][j]));
#pragma unroll
                for (int msk = 1; msk < 16; msk <<= 1) mx = fmaxf(mx, __shfl_xor(mx, msk));
                float mn = fmaxf(m_run[j], mx);
                alpha[j] = __expf(m_run[j] - mn);
                m_run[j] = mn;
                tsum[j] = 0.f;
            }
#pragma unroll
            for (int ct = 0; ct < 4; ++ct)
#pragma unroll
                for (int j = 0; j < 4; ++j) {
                    float pp = __expf(sc[ct][j] - m_run[j]);
                    sc[ct][j] = pp;
                    tsum[j] += pp;
                }
#pragma unroll
            for (int j = 0; j < 4; ++j) {
                float sm = tsum[j];
#pragma unroll
                for (int msk = 1; msk < 16; msk <<= 1) sm += __shfl_xor(sm, msk);
                l_run[j] = l_run[j] * alpha[j] + sm;
            }
#pragma unroll
            for (int dt = 0; dt < 8; ++dt)
#pragma unroll
                for (int j = 0; j < 4; ++j) oacc[dt][j] *= alpha[j];

            // ---- P (C-layout) -> per-wave LDS -> A-fragments ----
#pragma unroll
            for (int ct = 0; ct < 4; ++ct)
#pragma unroll
                for (int j = 0; j < 4; ++j)
                    P_lds[wid][l4 * 4 + j][ct * 16 + l15] = f2bf(sc[ct][j]);
            asm volatile("s_waitcnt lgkmcnt(0)" ::: "memory");
            // ---- PV from LDS ----
#pragma unroll
            for (int kk = 0; kk < 2; ++kk) {
                bf16x8 aP = *reinterpret_cast<const bf16x8*>(&P_lds[wid][l15][kk * 32 + l4 * 8]);
#pragma unroll
                for (int dt = 0; dt < 8; ++dt) {
                    bf16x8 bV = *reinterpret_cast<const bf16x8*>(
                        &Vs[cur][(dt * 16 + l15) * 64 + (((kk * 4 + l4) ^ (l15 & 7)) << 3)]);
                    oacc[dt] = __builtin_amdgcn_mfma_f32_16x16x32_bf16(aP, bV, oacc[dt], 0, 0, 0);
                }
            }
            asm volatile("s_waitcnt lgkmcnt(0)\n\ts_barrier" ::: "memory");
        }

        float inv_l[4];
#pragma unroll
        for (int j = 0; j < 4; ++j) inv_l[j] = 1.f / l_run[j];
        unsigned short* op = out + (size_t)(b * 2048 + qrow0 + l4 * 4) * 2048 + h * 128 + l15;
#pragma unroll
        for (int dt = 0; dt < 8; ++dt)
#pragma unroll
            for (int j = 0; j < 4; ++j)
                op[(size_t)j * 2048 + dt * 16] = f2bf(oacc[dt][j] * inv_l[j]);
    }
}

// ---------------- launch ----------------
extern "C" void kernel_launch(void* const* d_in, const int* in_sizes, int n_in,
                              void* d_out, int out_size, void* d_ws, size_t ws_size,
                              hipStream_t stream) {
    const float* hidden = (const float*)d_in[0];
    const float* ln1_g = (const float*)d_in[1];
    const float* ln1_b = (const float*)d_in[2];
    const float* w_attn = (const float*)d_in[3];
    const float* b_attn = (const float*)d_in[4];
    const float* w_o = (const float*)d_in[5];
    const float* b_o = (const float*)d_in[6];
    const float* ln2_g = (const float*)d_in[7];
    const float* ln2_b = (const float*)d_in[8];
    const float* w_fc = (const float*)d_in[9];
    const float* b_fc = (const float*)d_in[10];
    const float* w_fcp = (const float*)d_in[11];
    const float* b_fcp = (const float*)d_in[12];
    float* outp = (float*)d_out;

    if (ws_size < 268435456u) return; // need 256 MiB scratch

    char* ws = (char*)d_ws;
    unsigned short* wT_attn = (unsigned short*)(ws + 0);          // [6144][2048]
    unsigned short* wT_o    = (unsigned short*)(ws + 25165824);   // [2048][2048]
    unsigned short* wT_fc   = (unsigned short*)(ws + 33554432);   // [8192][2048]
    unsigned short* wT_proj = (unsigned short*)(ws + 67108864);   // [2048][8192]
    unsigned short* buf_x   = (unsigned short*)(ws + 100663296);  // [8192][2048] (x1 / attn / x2)
    unsigned short* qkv_b   = (unsigned short*)(ws + 134217728);  // [8192][6144]
    unsigned short* vtb     = (unsigned short*)(ws + 234881024);  // [64*128][2048]
    unsigned short* act_b   = qkv_b;                              // [8192][8192] overlays qkv+vt

    // 1. weight convert+transpose to bf16 [N][K]
    k_transpose_w<<<dim3(32, 96), 256, 0, stream>>>(w_attn, wT_attn, 2048, 6144);
    k_transpose_w<<<dim3(32, 32), 256, 0, stream>>>(w_o, wT_o, 2048, 2048);
    k_transpose_w<<<dim3(32, 128), 256, 0, stream>>>(w_fc, wT_fc, 2048, 8192);
    k_transpose_w<<<dim3(128, 32), 256, 0, stream>>>(w_fcp, wT_proj, 8192, 2048);
    // 2. LN1: hidden -> bf16 x
    k_layernorm<<<8192, 256, 0, stream>>>(hidden, ln1_g, ln1_b, buf_x);
    // 3. qkv = x @ w_attn + b_attn (Q cols pre-scaled by Dh^-0.5)
    k_gemm256<0><<<768, 512, 0, stream>>>(buf_x, wT_attn, b_attn, (const float*)nullptr,
                                          (void*)qkv_b, 8192, 6144, 2048,
                                          2048, 0.08838834764831845f, 24);
    // 4. V -> Vt [bh][d][s]
    k_transpose_v<<<dim3(32, 2, 64), 256, 0, stream>>>(qkv_b, vtb);
    // 5. causal flash attention -> buf_x (bf16)
    k_attn<<<1024, 256, 0, stream>>>(qkv_b, vtb, buf_x);
    // 6. hidden2 = attn @ w_o + b_o + hidden -> d_out (f32)
    k_gemm256<1><<<256, 512, 0, stream>>>(buf_x, wT_o, b_o, hidden,
                                          d_out, 8192, 2048, 2048, 0, 1.f, 8);
    // 7. LN2: d_out -> bf16 x2
    k_layernorm<<<8192, 256, 0, stream>>>(outp, ln2_g, ln2_b, buf_x);
    // 8. act = gelu(x2 @ w_fc + b_fc) -> bf16
    k_gemm256<2><<<1024, 512, 0, stream>>>(buf_x, wT_fc, b_fc, (const float*)nullptr,
                                           (void*)act_b, 8192, 8192, 2048, 0, 1.f, 32);
    // 9. out = act @ w_fc_proj + b_fc_proj + hidden2 (in-place on d_out)
    k_gemm256<1><<<256, 512, 0, stream>>>(act_b, wT_proj, b_fcp, outp,
                                          d_out, 8192, 2048, 8192, 0, 1.f, 8);
}

// Round 12
// 1120.989 us; speedup vs baseline: 1.0127x; 1.0127x over previous
//
#include <hip/hip_runtime.h>
#include <hip/hip_bf16.h>

#define DEVI __device__ __forceinline__

typedef __attribute__((ext_vector_type(8))) __bf16 bf16x8;
typedef __attribute__((ext_vector_type(4))) float f32x4;
typedef __attribute__((ext_vector_type(8))) unsigned short ushort8;

DEVI unsigned short f2bf(float f) {
    union { float f; unsigned u; } v; v.f = f;
    unsigned r = v.u + 0x7fffu + ((v.u >> 16) & 1u);
    return (unsigned short)(r >> 16);
}

DEVI void load_lds_16(const void* g, void* l) {
    __builtin_amdgcn_global_load_lds(
        (const __attribute__((address_space(1))) void*)g,
        (__attribute__((address_space(3))) void*)l, 16, 0, 0);
}

// ---------------- weight transpose+convert: in [K][N] f32 -> out [N][K] bf16 ----------------
__global__ __launch_bounds__(256) void k_transpose_w(const float* __restrict__ in,
                                                     unsigned short* __restrict__ out,
                                                     int K, int N) {
    __shared__ float tile[64][65];
    const int tk = blockIdx.x * 64, tn = blockIdx.y * 64;
    const int t = threadIdx.x;
    const int c4 = (t & 15) * 4, r0 = t >> 4;
#pragma unroll
    for (int p = 0; p < 4; ++p) {
        int r = r0 + p * 16;
        float4 v = *reinterpret_cast<const float4*>(&in[(size_t)(tk + r) * N + tn + c4]);
        tile[r][c4 + 0] = v.x; tile[r][c4 + 1] = v.y;
        tile[r][c4 + 2] = v.z; tile[r][c4 + 3] = v.w;
    }
    __syncthreads();
#pragma unroll
    for (int p = 0; p < 4; ++p) {
        int n = r0 + p * 16;
        ushort4 o;
        o.x = f2bf(tile[c4 + 0][n]); o.y = f2bf(tile[c4 + 1][n]);
        o.z = f2bf(tile[c4 + 2][n]); o.w = f2bf(tile[c4 + 3][n]);
        *reinterpret_cast<ushort4*>(&out[(size_t)(tn + n) * K + tk + c4]) = o;
    }
}

// ---------------- layernorm: fp32 [rows][2048] -> bf16, one block per row ----------------
__global__ __launch_bounds__(256) void k_layernorm(const float* __restrict__ x,
                                                   const float* __restrict__ g,
                                                   const float* __restrict__ bb,
                                                   unsigned short* __restrict__ out) {
    const int row = blockIdx.x;
    const int t = threadIdx.x;
    const float* xr = x + (size_t)row * 2048 + t * 8;
    float4 v0 = *reinterpret_cast<const float4*>(xr);
    float4 v1 = *reinterpret_cast<const float4*>(xr + 4);
    float s = (v0.x + v0.y) + (v0.z + v0.w) + (v1.x + v1.y) + (v1.z + v1.w);
    float ss = (v0.x * v0.x + v0.y * v0.y) + (v0.z * v0.z + v0.w * v0.w)
             + (v1.x * v1.x + v1.y * v1.y) + (v1.z * v1.z + v1.w * v1.w);
#pragma unroll
    for (int m = 1; m < 64; m <<= 1) { s += __shfl_xor(s, m); ss += __shfl_xor(ss, m); }
    __shared__ float red[8];
    if ((t & 63) == 0) { red[t >> 6] = s; red[4 + (t >> 6)] = ss; }
    __syncthreads();
    s = (red[0] + red[1]) + (red[2] + red[3]);
    ss = (red[4] + red[5]) + (red[6] + red[7]);
    const float mu = s * (1.f / 2048.f);
    const float rstd = rsqrtf(ss * (1.f / 2048.f) - mu * mu + 1e-5f);
    const float4 g0 = *reinterpret_cast<const float4*>(g + t * 8);
    const float4 g1 = *reinterpret_cast<const float4*>(g + t * 8 + 4);
    const float4 b0 = *reinterpret_cast<const float4*>(bb + t * 8);
    const float4 b1 = *reinterpret_cast<const float4*>(bb + t * 8 + 4);
    ushort8 o;
    o[0] = f2bf((v0.x - mu) * rstd * g0.x + b0.x);
    o[1] = f2bf((v0.y - mu) * rstd * g0.y + b0.y);
    o[2] = f2bf((v0.z - mu) * rstd * g0.z + b0.z);
    o[3] = f2bf((v0.w - mu) * rstd * g0.w + b0.w);
    o[4] = f2bf((v1.x - mu) * rstd * g1.x + b1.x);
    o[5] = f2bf((v1.y - mu) * rstd * g1.y + b1.y);
    o[6] = f2bf((v1.z - mu) * rstd * g1.z + b1.z);
    o[7] = f2bf((v1.w - mu) * rstd * g1.w + b1.w);
    *reinterpret_cast<ushort8*>(out + (size_t)row * 2048 + t * 8) = o;
}

// ======================= GEMM 256x256, 8-wave, 8-PHASE schedule (R9-proven) =======================
// A[M][K] bf16 * Bt[N][K] bf16 + bias. K-half LDS slots: per operand 4 slots of 16KB
// (slot = buf*2 + khalf). Pairline layout: pairline p (128B) holds rows {2p,2p+1} of a
// 32-k half; physical granule g' = ((rowparity<<2)|kgranule) ^ (p&7). Staging is linear
// (global_load_lds dest = base + lane*16) with pre-swizzled per-lane global source.
// Per phase: {ds_reads; stage 1 half-tile (2 loads); barrier; 16 MFMA (compiler
// inserts fine-grained lgkmcnt for the register deps); vmcnt(8); barrier}.
// R12: epilogue V-redirect for the qkv GEMM — cols>=4096 (V) are written directly in
// vt[bh][d][s] layout (vtout != nullptr), eliminating the separate V-transpose kernel.
// Sync structure is byte-identical to the R9 template (passed, stable); the R11
// single-barrier 3-slot variant raced post-timing and is abandoned.
template <int EPI>
__global__ __launch_bounds__(512, 1) void k_gemm256(const unsigned short* __restrict__ A,
                                                    const unsigned short* __restrict__ Bt,
                                                    const float* __restrict__ bias,
                                                    const float* __restrict__ res,
                                                    void* __restrict__ outv,
                                                    unsigned short* __restrict__ vtout,
                                                    int M, int N, int K,
                                                    int scale_cols, float scale, int gx) {
    __shared__ alignas(16) unsigned short LDS[65536];   // A: bytes [0,64K), B: [64K,128K)

    // bijective XCD swizzle (nwg % 8 == 0 for all our grids)
    const int nwg = gridDim.x;
    const int bid = blockIdx.x;
    const int wg = (bid & 7) * (nwg >> 3) + (bid >> 3);
    const int bn = (wg % gx) * 256;
    const int bm = (wg / gx) * 256;

    const int t = threadIdx.x, lane = t & 63, wid = t >> 6;
    const int wr = wid >> 2, wn = wid & 3;          // wave: row-half (0,1) x col-quarter (0..3)
    const int l15 = lane & 15, l4 = lane >> 4;      // frag: row=l15, k-granule=l4

    // ds_read thread base within a 16KB slot: q=l15>>1, rp=l15&1, g'=((rp<<2)|l4)^q
    const int q_ = l15 >> 1, rp_ = l15 & 1;
    const int Toff = q_ * 128 + (((((rp_ << 2) | l4)) ^ q_) << 4);
    const char* pTA = (const char*)LDS + wr * 8192 + Toff;
    const char* pTB = (const char*)LDS + 65536 + wn * 4096 + Toff;

    // staging source mapping: lane covers pairline (wid*2+i)*8 + (lane>>3), phys granule lane&7
    const int glog = (lane & 7) ^ (lane >> 3);
    const int s_rp = glog >> 2, s_j = glog & 3;
    const int s_row = wid * 32 + 2 * (lane >> 3) + s_rp;     // +16 for i=1
    const unsigned short* pAs0 = A  + (size_t)(bm + s_row) * K + s_j * 8;
    const unsigned short* pAs1 = pAs0 + (size_t)16 * K;
    const unsigned short* pBs0 = Bt + (size_t)(bn + s_row) * K + s_j * 8;
    const unsigned short* pBs1 = pBs0 + (size_t)16 * K;
    char* dA = (char*)LDS + wid * 2048;            // + SLOT*16384 (+1024 for i=1)
    char* dB = (char*)LDS + 65536 + wid * 2048;

    const int NT = K >> 6;
    const int NI = NT >> 1;     // >= 2 for all our shapes

    f32x4 acc[8][4] = {};
    bf16x8 xa[4], xb[4], bK0[4], bK1[4];

#define STGA(SLOT, KOE) do { \
    load_lds_16(pAs0 + (KOE), dA + (SLOT) * 16384); \
    load_lds_16(pAs1 + (KOE), dA + (SLOT) * 16384 + 1024); } while (0)
#define STGB(SLOT, KOE) do { \
    load_lds_16(pBs0 + (KOE), dB + (SLOT) * 16384); \
    load_lds_16(pBs1 + (KOE), dB + (SLOT) * 16384 + 1024); } while (0)
#define RDA4(DST, SLOT, F0) do { _Pragma("unroll") \
    for (int f_ = 0; f_ < 4; ++f_) \
        DST[f_] = *reinterpret_cast<const bf16x8*>(pTA + (SLOT) * 16384 + ((F0) + f_) * 1024); } while (0)
#define RDB4(DST, SLOT) do { _Pragma("unroll") \
    for (int n_ = 0; n_ < 4; ++n_) \
        DST[n_] = *reinterpret_cast<const bf16x8*>(pTB + (SLOT) * 16384 + n_ * 1024); } while (0)
#define MM16(F0, AV, BV) do { _Pragma("unroll") \
    for (int f_ = 0; f_ < 4; ++f_) \
        _Pragma("unroll") \
        for (int n_ = 0; n_ < 4; ++n_) \
            acc[(F0) + f_][n_] = __builtin_amdgcn_mfma_f32_16x16x32_bf16( \
                AV[f_], BV[n_], acc[(F0) + f_][n_], 0, 0, 0); } while (0)
#define PHASE(RDS, STG, F0, AV, BV, TAIL) do { \
    RDS; STG; \
    asm volatile("s_barrier" ::: "memory"); \
    __builtin_amdgcn_s_setprio(1); \
    MM16(F0, AV, BV); \
    __builtin_amdgcn_s_setprio(0); \
    TAIL; } while (0)
#define VMBAR8 asm volatile("s_waitcnt vmcnt(8)\n\ts_barrier" ::: "memory")
#define VMBAR0 asm volatile("s_waitcnt vmcnt(0)\n\ts_barrier" ::: "memory")
#define BARONLY asm volatile("s_barrier" ::: "memory")

    // prologue: slot0=KT0.kh0, slot1=KT0.kh1, slot2=KT1.kh0 (12 loads, FIFO order)
    STGA(0, 0);  STGB(0, 0);
    STGA(1, 32); STGB(1, 32);
    STGA(2, 64); STGB(2, 64);
    asm volatile("s_waitcnt vmcnt(8)\n\ts_barrier" ::: "memory");

    int kof = 0;
    for (int i = 0; i < NI - 1; ++i, kof += 128) {
        // ph1: slot0 (buf0.kh0); stage slot3 <- KT(2i+1).kh1
        PHASE(RDB4(bK0, 0); RDA4(xa, 0, 0), STGA(3, kof + 96), 0, xa, bK0, VMBAR8);
        // ph2
        PHASE(RDA4(xb, 0, 4), STGB(3, kof + 96), 4, xb, bK0, VMBAR8);
        // ph3: slot1 (buf0.kh1); stage slot0 <- KT(2i+2).kh0
        PHASE(RDB4(bK1, 1); RDA4(xa, 1, 0), STGA(0, kof + 128), 0, xa, bK1, VMBAR8);
        // ph4
        PHASE(RDA4(xb, 1, 4), STGB(0, kof + 128), 4, xb, bK1, VMBAR8);
        // ph5: slot2 (buf1.kh0); stage slot1 <- KT(2i+2).kh1
        PHASE(RDB4(bK0, 2); RDA4(xa, 2, 0), STGA(1, kof + 160), 0, xa, bK0, VMBAR8);
        // ph6
        PHASE(RDA4(xb, 2, 4), STGB(1, kof + 160), 4, xb, bK0, VMBAR8);
        // ph7: slot3 (buf1.kh1); stage slot2 <- KT(2i+3).kh0
        PHASE(RDB4(bK1, 3); RDA4(xa, 3, 0), STGA(2, kof + 192), 0, xa, bK1, VMBAR8);
        // ph8
        PHASE(RDA4(xb, 3, 4), STGB(2, kof + 192), 4, xb, bK1, VMBAR8);
    }
    // final iteration: stage only slot3 (KT(NT-1).kh1), drain at ph2, no further vmcnt
    PHASE(RDB4(bK0, 0); RDA4(xa, 0, 0), STGA(3, kof + 96), 0, xa, bK0, VMBAR8);
    PHASE(RDA4(xb, 0, 4), STGB(3, kof + 96), 4, xb, bK0, VMBAR0);
    PHASE(RDB4(bK1, 1); RDA4(xa, 1, 0), (void)0, 0, xa, bK1, BARONLY);
    PHASE(RDA4(xb, 1, 4), (void)0, 4, xb, bK1, BARONLY);
    PHASE(RDB4(bK0, 2); RDA4(xa, 2, 0), (void)0, 0, xa, bK0, BARONLY);
    PHASE(RDA4(xb, 2, 4), (void)0, 4, xb, bK0, BARONLY);
    PHASE(RDB4(bK1, 3); RDA4(xa, 3, 0), (void)0, 0, xa, bK1, BARONLY);
    PHASE(RDA4(xb, 3, 4), (void)0, 4, xb, bK1, BARONLY);

#undef STGA
#undef STGB
#undef RDA4
#undef RDB4
#undef MM16
#undef PHASE
#undef VMBAR8
#undef VMBAR0
#undef BARONLY

    // epilogue
    const int row0 = bm + wr * 128 + l4 * 4;
    const int col0 = bn + wn * 64 + l15;
#pragma unroll
    for (int n = 0; n < 4; ++n) {
        const int col = col0 + n * 16;
        const float bv = bias[col];
        if (EPI == 0 && vtout != nullptr && col >= 4096) {
            // V redirect: vt[(b*16+h)][d][s]; s-contiguous per j-group
            const int hh = (col - 4096) >> 7;
            const int d = col & 127;
#pragma unroll
            for (int f = 0; f < 8; ++f) {
                const int row = row0 + f * 16;
                const int b_ = row >> 11;
                unsigned short* vp = vtout + ((size_t)(b_ * 16 + hh) * 128 + d) * 2048 + (row & 2047);
#pragma unroll
                for (int j = 0; j < 4; ++j)
                    vp[j] = f2bf(acc[f][n][j] + bv);
            }
        } else {
            const float qs = (EPI == 0 && col < scale_cols) ? scale : 1.f;
#pragma unroll
            for (int f = 0; f < 8; ++f) {
                const int row = row0 + f * 16;
#pragma unroll
                for (int j = 0; j < 4; ++j) {
                    float v = acc[f][n][j] + bv;
                    const size_t idx = (size_t)(row + j) * N + col;
                    if (EPI == 0) {
                        ((unsigned short*)outv)[idx] = f2bf(v * qs);
                    } else if (EPI == 1) {
                        ((float*)outv)[idx] = v + res[idx];
                    } else {
                        float u = v + 0.044715f * v * v * v;
                        u = fminf(fmaxf(u, -40.f), 40.f);
                        float e = __expf(1.5957691216057308f * u); // 2*sqrt(2/pi)
                        float th = (e - 1.f) / (e + 1.f);
                        ((unsigned short*)outv)[idx] = f2bf(0.5f * v * (1.f + th));
                    }
                }
            }
        }
    }
}

// ---------------- flash attention v2: LDS-staged K/V, dbuf, pair-balanced, causal ----------------
// grid = 1024: xcd = blk&7, idx = blk>>3, bh = xcd*8 + idx/16, pair = idx%16.
// Block handles q-tiles {31-pair, pair} (64 rows each) => uniform 33 k-tile iters.
__global__ __launch_bounds__(256) void k_attn(const unsigned short* __restrict__ qkv,
                                              const unsigned short* __restrict__ vt,
                                              unsigned short* __restrict__ out) {
    __shared__ alignas(16) unsigned short Ks[2][64 * 128];   // [s][d], granule-swizzled
    __shared__ alignas(16) unsigned short Vs[2][128 * 64];   // [d][s], granule-swizzled
    __shared__ alignas(16) unsigned short P_lds[4][16][72];

    const int p = blockIdx.x;
    const int bh = (p & 7) * 8 + ((p >> 3) >> 4);
    const int pair = (p >> 3) & 15;
    const int b = bh >> 4, h = bh & 15;
    const int t = threadIdx.x, lane = t & 63, wid = t >> 6;
    const int l15 = lane & 15, l4 = lane >> 4;

    // staging geometry (per wave: 4 K-chunks + 4 V-chunks of 1KB)
    const int kq = wid * 4;                 // first chunk index of this wave
    const int k_r0 = kq * 4 + (lane >> 4);  // K row for chunk kq (+i*4)
    const int k_g0 = lane & 15;             // physical granule (16B) within K row
    const int v_d0 = kq * 8 + (lane >> 3);  // V row (d) for chunk kq (+i*8)
    const int v_g0 = lane & 7;              // physical granule within V row

#pragma unroll
    for (int qi = 0; qi < 2; ++qi) {
        const int qt = qi ? pair : (31 - pair);
        const int qrow0 = qt * 64 + wid * 16;
        const int nt = qt + 1;

        // Q fragments (A-operand): row l15, k = l4*8 + s*32
        const unsigned short* qp = qkv + (size_t)(b * 2048 + qrow0 + l15) * 6144 + h * 128 + l4 * 8;
        bf16x8 aQ[4];
#pragma unroll
        for (int s = 0; s < 4; ++s) aQ[s] = *reinterpret_cast<const bf16x8*>(qp + s * 32);

        f32x4 oacc[8] = {};
        float m_run[4], l_run[4];
#pragma unroll
        for (int j = 0; j < 4; ++j) { m_run[j] = -1e30f; l_run[j] = 0.f; }

        // prologue: stage tile 0 into buffer 0
        {
#pragma unroll
            for (int i = 0; i < 4; ++i) {
                const int r = k_r0 + i * 4;
                const unsigned short* src = qkv + (size_t)(b * 2048 + r) * 6144 + 2048
                                            + h * 128 + (size_t)(k_g0 ^ (r & 7)) * 8;
                load_lds_16(src, &Ks[0][(kq + i) * 512]);
            }
#pragma unroll
            for (int i = 0; i < 4; ++i) {
                const int d = v_d0 + i * 8;
                const unsigned short* src = vt + ((size_t)bh * 128 + d) * 2048
                                            + (size_t)(v_g0 ^ (d & 7)) * 8;
                load_lds_16(src, &Vs[0][(kq + i) * 512]);
            }
        }

        for (int ti = 0; ti < nt; ++ti) {
            const int cur = ti & 1;
            const int k0 = ti * 64;
            if (ti + 1 < nt) {
                const int kn = k0 + 64;
#pragma unroll
                for (int i = 0; i < 4; ++i) {
                    const int r = k_r0 + i * 4;
                    const unsigned short* src = qkv + (size_t)(b * 2048 + kn + r) * 6144 + 2048
                                                + h * 128 + (size_t)(k_g0 ^ (r & 7)) * 8;
                    load_lds_16(src, &Ks[cur ^ 1][(kq + i) * 512]);
                }
#pragma unroll
                for (int i = 0; i < 4; ++i) {
                    const int d = v_d0 + i * 8;
                    const unsigned short* src = vt + ((size_t)bh * 128 + d) * 2048 + kn
                                                + (size_t)(v_g0 ^ (d & 7)) * 8;
                    load_lds_16(src, &Vs[cur ^ 1][(kq + i) * 512]);
                }
                asm volatile("s_waitcnt vmcnt(8)\n\ts_barrier" ::: "memory");
            } else {
                asm volatile("s_waitcnt vmcnt(0)\n\ts_barrier" ::: "memory");
            }

            // ---- QK^T from LDS ----
            f32x4 sc[4] = {};
#pragma unroll
            for (int s = 0; s < 4; ++s)
#pragma unroll
                for (int ct = 0; ct < 4; ++ct) {
                    bf16x8 bKf = *reinterpret_cast<const bf16x8*>(
                        &Ks[cur][(ct * 16 + l15) * 128 + (((s * 4 + l4) ^ (l15 & 7)) << 3)]);
                    sc[ct] = __builtin_amdgcn_mfma_f32_16x16x32_bf16(aQ[s], bKf, sc[ct], 0, 0, 0);
                }

            if (k0 + 63 > qrow0) { // causal mask for diagonal-crossing tiles
#pragma unroll
                for (int ct = 0; ct < 4; ++ct) {
                    int colc = k0 + ct * 16 + l15;
#pragma unroll
                    for (int j = 0; j < 4; ++j)
                        if (colc > qrow0 + l4 * 4 + j) sc[ct][j] = -1e30f;
                }
            }
            // ---- online softmax ----
            float alpha[4], tsum[4];
#pragma unroll
            for (int j = 0; j < 4; ++j) {
                float mx = fmaxf(fmaxf(sc[0][j], sc[1][j]), fmaxf(sc[2][j], sc[3][j]));
#pragma unroll
                for (int msk = 1; msk < 16; msk <<= 1) mx = fmaxf(mx, __shfl_xor(mx, msk));
                float mn = fmaxf(m_run[j], mx);
                alpha[j] = __expf(m_run[j] - mn);
                m_run[j] = mn;
                tsum[j] = 0.f;
            }
#pragma unroll
            for (int ct = 0; ct < 4; ++ct)
#pragma unroll
                for (int j = 0; j < 4; ++j) {
                    float pp = __expf(sc[ct][j] - m_run[j]);
                    sc[ct][j] = pp;
                    tsum[j] += pp;
                }
#pragma unroll
            for (int j = 0; j < 4; ++j) {
                float sm = tsum[j];
#pragma unroll
                for (int msk = 1; msk < 16; msk <<= 1) sm += __shfl_xor(sm, msk);
                l_run[j] = l_run[j] * alpha[j] + sm;
            }
#pragma unroll
            for (int dt = 0; dt < 8; ++dt)
#pragma unroll
                for (int j = 0; j < 4; ++j) oacc[dt][j] *= alpha[j];

            // ---- P (C-layout) -> per-wave LDS -> A-fragments ----
#pragma unroll
            for (int ct = 0; ct < 4; ++ct)
#pragma unroll
                for (int j = 0; j < 4; ++j)
                    P_lds[wid][l4 * 4 + j][ct * 16 + l15] = f2bf(sc[ct][j]);
            asm volatile("s_waitcnt lgkmcnt(0)" ::: "memory");
            // ---- PV from LDS ----
#pragma unroll
            for (int kk = 0; kk < 2; ++kk) {
                bf16x8 aP = *reinterpret_cast<const bf16x8*>(&P_lds[wid][l15][kk * 32 + l4 * 8]);
#pragma unroll
                for (int dt = 0; dt < 8; ++dt) {
                    bf16x8 bV = *reinterpret_cast<const bf16x8*>(
                        &Vs[cur][(dt * 16 + l15) * 64 + (((kk * 4 + l4) ^ (l15 & 7)) << 3)]);
                    oacc[dt] = __builtin_amdgcn_mfma_f32_16x16x32_bf16(aP, bV, oacc[dt], 0, 0, 0);
                }
            }
            asm volatile("s_waitcnt lgkmcnt(0)\n\ts_barrier" ::: "memory");
        }

        float inv_l[4];
#pragma unroll
        for (int j = 0; j < 4; ++j) inv_l[j] = 1.f / l_run[j];
        unsigned short* op = out + (size_t)(b * 2048 + qrow0 + l4 * 4) * 2048 + h * 128 + l15;
#pragma unroll
        for (int dt = 0; dt < 8; ++dt)
#pragma unroll
            for (int j = 0; j < 4; ++j)
                op[(size_t)j * 2048 + dt * 16] = f2bf(oacc[dt][j] * inv_l[j]);
    }
}

// ---------------- launch ----------------
extern "C" void kernel_launch(void* const* d_in, const int* in_sizes, int n_in,
                              void* d_out, int out_size, void* d_ws, size_t ws_size,
                              hipStream_t stream) {
    const float* hidden = (const float*)d_in[0];
    const float* ln1_g = (const float*)d_in[1];
    const float* ln1_b = (const float*)d_in[2];
    const float* w_attn = (const float*)d_in[3];
    const float* b_attn = (const float*)d_in[4];
    const float* w_o = (const float*)d_in[5];
    const float* b_o = (const float*)d_in[6];
    const float* ln2_g = (const float*)d_in[7];
    const float* ln2_b = (const float*)d_in[8];
    const float* w_fc = (const float*)d_in[9];
    const float* b_fc = (const float*)d_in[10];
    const float* w_fcp = (const float*)d_in[11];
    const float* b_fcp = (const float*)d_in[12];
    float* outp = (float*)d_out;

    if (ws_size < 268435456u) return; // need 256 MiB scratch

    char* ws = (char*)d_ws;
    unsigned short* wT_attn = (unsigned short*)(ws + 0);          // [6144][2048]
    unsigned short* wT_o    = (unsigned short*)(ws + 25165824);   // [2048][2048]
    unsigned short* wT_fc   = (unsigned short*)(ws + 33554432);   // [8192][2048]
    unsigned short* wT_proj = (unsigned short*)(ws + 67108864);   // [2048][8192]
    unsigned short* buf_x   = (unsigned short*)(ws + 100663296);  // [8192][2048] (x1 / attn / x2)
    unsigned short* qkv_b   = (unsigned short*)(ws + 134217728);  // [8192][6144] (V cols unused)
    unsigned short* vtb     = (unsigned short*)(ws + 234881024);  // [64*128][2048]
    unsigned short* act_b   = qkv_b;                              // [8192][8192] overlays qkv+vt

    // 1. weight convert+transpose to bf16 [N][K]
    k_transpose_w<<<dim3(32, 96), 256, 0, stream>>>(w_attn, wT_attn, 2048, 6144);
    k_transpose_w<<<dim3(32, 32), 256, 0, stream>>>(w_o, wT_o, 2048, 2048);
    k_transpose_w<<<dim3(32, 128), 256, 0, stream>>>(w_fc, wT_fc, 2048, 8192);
    k_transpose_w<<<dim3(128, 32), 256, 0, stream>>>(w_fcp, wT_proj, 8192, 2048);
    // 2. LN1: hidden -> bf16 x
    k_layernorm<<<8192, 256, 0, stream>>>(hidden, ln1_g, ln1_b, buf_x);
    // 3. qkv = x @ w_attn + b_attn (Q cols pre-scaled by Dh^-0.5; V cols written
    //    directly into vtb[bh][d][s] — replaces the separate V-transpose kernel)
    k_gemm256<0><<<768, 512, 0, stream>>>(buf_x, wT_attn, b_attn, (const float*)nullptr,
                                          (void*)qkv_b, vtb, 8192, 6144, 2048,
                                          2048, 0.08838834764831845f, 24);
    // 4. causal flash attention -> buf_x (bf16)
    k_attn<<<1024, 256, 0, stream>>>(qkv_b, vtb, buf_x);
    // 5. hidden2 = attn @ w_o + b_o + hidden -> d_out (f32)
    k_gemm256<1><<<256, 512, 0, stream>>>(buf_x, wT_o, b_o, hidden,
                                          d_out, (unsigned short*)nullptr,
                                          8192, 2048, 2048, 0, 1.f, 8);
    // 6. LN2: d_out -> bf16 x2
    k_layernorm<<<8192, 256, 0, stream>>>(outp, ln2_g, ln2_b, buf_x);
    // 7. act = gelu(x2 @ w_fc + b_fc) -> bf16
    k_gemm256<2><<<1024, 512, 0, stream>>>(buf_x, wT_fc, b_fc, (const float*)nullptr,
                                           (void*)act_b, (unsigned short*)nullptr,
                                           8192, 8192, 2048, 0, 1.f, 32);
    // 8. out = act @ w_fc_proj + b_fc_proj + hidden2 (in-place on d_out)
    k_gemm256<1><<<256, 512, 0, stream>>>(act_b, wT_proj, b_fcp, outp,
                                          d_out, (unsigned short*)nullptr,
                                          8192, 2048, 8192, 0, 1.f, 8);
}